// Round 1
// baseline (149.406 us; speedup 1.0000x reference)
//
#include <hip/hip_runtime.h>

// Problem constants (match reference).
constexpr int Hh = 256;
constexpr int Ww = 256;
constexpr int Dd = 256;
constexpr int NB = 2048;

// ---------------------------------------------------------------------------
// Pass 1: row-prefix along W.  One thread per (h, d); lanes cover consecutive
// d -> every load/store is a coalesced 256B wave transaction.
// ---------------------------------------------------------------------------
__global__ void __launch_bounds__(256) sat_row_prefix(const float* __restrict__ feat,
                                                      float* __restrict__ sat) {
    int t = blockIdx.x * blockDim.x + threadIdx.x;   // [0, H*D)
    int h = t >> 8;          // t / 256
    int d = t & 255;         // t % 256
    const float* src = feat + ((size_t)h * Ww) * Dd + d;
    float*       dst = sat  + ((size_t)h * Ww) * Dd + d;
    float acc = 0.0f;
#pragma unroll 8
    for (int w = 0; w < Ww; ++w) {
        acc += src[(size_t)w * Dd];
        dst[(size_t)w * Dd] = acc;
    }
}

// ---------------------------------------------------------------------------
// Pass 2: column-prefix along H (in place on sat). One thread per (w, d).
// ---------------------------------------------------------------------------
__global__ void __launch_bounds__(256) sat_col_prefix(float* __restrict__ sat) {
    int t = blockIdx.x * blockDim.x + threadIdx.x;   // [0, W*D)
    int w = t >> 8;
    int d = t & 255;
    float* p = sat + ((size_t)w) * Dd + d;
    float acc = 0.0f;
#pragma unroll 8
    for (int h = 0; h < Hh; ++h) {
        float* q = p + (size_t)h * Ww * Dd;
        acc += *q;
        *q = acc;
    }
}

// ---------------------------------------------------------------------------
// Pass 3: per-(box, channel) 4-corner SAT lookup.
// Block = 256 threads = one box (all 256 channels): box loads + bound math
// are wave-uniform; SAT reads coalesced across d.
// Bounds math replicates the f32 JAX semantics exactly:
//   lo = max(0, floor(lo_f*size));  hi = rint(hi_f*size + 0.5)  (ties-to-even)
//   hi = min(size, max(lo+1, hi))
// ---------------------------------------------------------------------------
__global__ void __launch_bounds__(256) roi_pool_sat(const float* __restrict__ sat,
                                                    const float* __restrict__ boxes,
                                                    float* __restrict__ out) {
    int t = blockIdx.x * blockDim.x + threadIdx.x;   // [0, NB*D)
    int n = t >> 8;
    int d = t & 255;

    float x1 = boxes[n * 4 + 0];
    float y1 = boxes[n * 4 + 1];
    float x2 = boxes[n * 4 + 2];
    float y2 = boxes[n * 4 + 3];

    int cl = max(0, (int)floorf(x1 * 256.0f));
    int ch = (int)rintf(x2 * 256.0f + 0.5f);
    ch = min(Ww, max(cl + 1, ch));

    int rl = max(0, (int)floorf(y1 * 256.0f));
    int rh = (int)rintf(y2 * 256.0f + 0.5f);
    rh = min(Hh, max(rl + 1, rh));

    // S(r, c, d) with r = rh-1 / rl-1, c = ch-1 / cl-1; lo-1 < 0 terms are 0.
    const float* Sbr = sat + (((size_t)(rh - 1) * Ww) + (ch - 1)) * Dd + d;
    float s = *Sbr;
    if (cl > 0) s -= sat[(((size_t)(rh - 1) * Ww) + (cl - 1)) * Dd + d];
    if (rl > 0) {
        s -= sat[(((size_t)(rl - 1) * Ww) + (ch - 1)) * Dd + d];
        if (cl > 0) s += sat[(((size_t)(rl - 1) * Ww) + (cl - 1)) * Dd + d];
    }

    float count = (float)((rh - rl) * (ch - cl));
    out[(size_t)n * Dd + d] = s / count;
}

// ---------------------------------------------------------------------------
// Fallback (only if ws too small for the 64 MiB SAT): direct summation.
// One block (256 threads = 256 channels) per box.
// ---------------------------------------------------------------------------
__global__ void __launch_bounds__(256) roi_pool_naive(const float* __restrict__ feat,
                                                      const float* __restrict__ boxes,
                                                      float* __restrict__ out) {
    int n = blockIdx.x;
    int d = threadIdx.x;

    float x1 = boxes[n * 4 + 0];
    float y1 = boxes[n * 4 + 1];
    float x2 = boxes[n * 4 + 2];
    float y2 = boxes[n * 4 + 3];

    int cl = max(0, (int)floorf(x1 * 256.0f));
    int ch = (int)rintf(x2 * 256.0f + 0.5f);
    ch = min(Ww, max(cl + 1, ch));
    int rl = max(0, (int)floorf(y1 * 256.0f));
    int rh = (int)rintf(y2 * 256.0f + 0.5f);
    rh = min(Hh, max(rl + 1, rh));

    float s = 0.0f;
    for (int r = rl; r < rh; ++r) {
        const float* row = feat + ((size_t)r * Ww) * Dd + d;
        for (int c = cl; c < ch; ++c) s += row[(size_t)c * Dd];
    }
    float count = (float)((rh - rl) * (ch - cl));
    out[(size_t)n * Dd + d] = s / count;
}

extern "C" void kernel_launch(void* const* d_in, const int* in_sizes, int n_in,
                              void* d_out, int out_size, void* d_ws, size_t ws_size,
                              hipStream_t stream) {
    const float* feat  = (const float*)d_in[0];   // (256,256,256) f32
    const float* boxes = (const float*)d_in[1];   // (2048,4) f32
    float* out = (float*)d_out;                   // (2048,256) f32

    const size_t sat_bytes = (size_t)Hh * Ww * Dd * sizeof(float);  // 64 MiB

    if (ws_size >= sat_bytes) {
        float* sat = (float*)d_ws;
        sat_row_prefix<<<(Hh * Dd) / 256, 256, 0, stream>>>(feat, sat);
        sat_col_prefix<<<(Ww * Dd) / 256, 256, 0, stream>>>(sat);
        roi_pool_sat<<<(NB * Dd) / 256, 256, 0, stream>>>(sat, boxes, out);
    } else {
        roi_pool_naive<<<NB, 256, 0, stream>>>(feat, boxes, out);
    }
}

// Round 2
// 125.295 us; speedup vs baseline: 1.1924x; 1.1924x over previous
//
#include <hip/hip_runtime.h>

// Problem constants (match reference).
constexpr int Hh = 256;
constexpr int Ww = 256;
constexpr int Dd = 256;
constexpr int NB = 2048;

constexpr int CH = 16;   // chunk length along the scan axis
constexpr int NC = 16;   // chunks per scan axis (256/16)
constexpr int DL = 64;   // d-lanes per block (one wave-width)

// ---------------------------------------------------------------------------
// Pass 1: row-prefix along W. One block covers one (row h, 64-channel slice):
// 16 chunks x 16 elements held in registers, chunk totals scanned via LDS.
// Grid = H * (D/DL) = 1024 blocks, 1024 thr -> 32 waves/CU occupancy.
// Wave lanes span d -> every load/store is a coalesced 256B transaction.
// ---------------------------------------------------------------------------
__global__ void __launch_bounds__(1024) sat_row_prefix(const float* __restrict__ feat,
                                                       float* __restrict__ sat) {
    const int tid = threadIdx.x;
    const int dl  = tid & (DL - 1);
    const int wc  = tid >> 6;            // chunk index, wave-uniform
    const int h   = blockIdx.x >> 2;     // D/DL = 4 slices
    const int dq  = blockIdx.x & 3;
    const int d   = dq * DL + dl;

    const size_t base = ((size_t)h * Ww + (size_t)wc * CH) * Dd + d;
    const float* src = feat + base;
    float*       dst = sat + base;

    float v[CH];
#pragma unroll
    for (int j = 0; j < CH; ++j) v[j] = src[(size_t)j * Dd];
#pragma unroll
    for (int j = 1; j < CH; ++j) v[j] += v[j - 1];

    __shared__ float cs[NC][DL];
    cs[wc][dl] = v[CH - 1];
    __syncthreads();

    float off = 0.0f;
    for (int k = 0; k < wc; ++k) off += cs[k][dl];   // wc wave-uniform: no divergence

#pragma unroll
    for (int j = 0; j < CH; ++j) dst[(size_t)j * Dd] = v[j] + off;
}

// ---------------------------------------------------------------------------
// Pass 2: column-prefix along H, in place on sat. Same structure; scan-axis
// stride is W*D. One block = one (column w, 64-channel slice).
// ---------------------------------------------------------------------------
__global__ void __launch_bounds__(1024) sat_col_prefix(float* __restrict__ sat) {
    const int tid = threadIdx.x;
    const int dl  = tid & (DL - 1);
    const int hc  = tid >> 6;            // chunk index, wave-uniform
    const int w   = blockIdx.x >> 2;
    const int dq  = blockIdx.x & 3;
    const int d   = dq * DL + dl;

    float* p = sat + (size_t)w * Dd + d + (size_t)hc * CH * Ww * Dd;
    const size_t stride = (size_t)Ww * Dd;

    float v[CH];
#pragma unroll
    for (int j = 0; j < CH; ++j) v[j] = p[(size_t)j * stride];
#pragma unroll
    for (int j = 1; j < CH; ++j) v[j] += v[j - 1];

    __shared__ float cs[NC][DL];
    cs[hc][dl] = v[CH - 1];
    __syncthreads();

    float off = 0.0f;
    for (int k = 0; k < hc; ++k) off += cs[k][dl];

#pragma unroll
    for (int j = 0; j < CH; ++j) p[(size_t)j * stride] = v[j] + off;
}

// ---------------------------------------------------------------------------
// Pass 3: per-(box, channel) 4-corner SAT lookup. Block = one box, lanes
// span d (coalesced). Bounds math replicates f32 JAX semantics exactly:
//   lo = max(0, floor(lo_f*size));  hi = rint(hi_f*size + 0.5)  (ties-even)
//   hi = min(size, max(lo+1, hi))
// ---------------------------------------------------------------------------
__global__ void __launch_bounds__(256) roi_pool_sat(const float* __restrict__ sat,
                                                    const float* __restrict__ boxes,
                                                    float* __restrict__ out) {
    int t = blockIdx.x * blockDim.x + threadIdx.x;   // [0, NB*D)
    int n = t >> 8;
    int d = t & 255;

    float x1 = boxes[n * 4 + 0];
    float y1 = boxes[n * 4 + 1];
    float x2 = boxes[n * 4 + 2];
    float y2 = boxes[n * 4 + 3];

    int cl = max(0, (int)floorf(x1 * 256.0f));
    int ch = (int)rintf(x2 * 256.0f + 0.5f);
    ch = min(Ww, max(cl + 1, ch));

    int rl = max(0, (int)floorf(y1 * 256.0f));
    int rh = (int)rintf(y2 * 256.0f + 0.5f);
    rh = min(Hh, max(rl + 1, rh));

    float s = sat[(((size_t)(rh - 1) * Ww) + (ch - 1)) * Dd + d];
    if (cl > 0) s -= sat[(((size_t)(rh - 1) * Ww) + (cl - 1)) * Dd + d];
    if (rl > 0) {
        s -= sat[(((size_t)(rl - 1) * Ww) + (ch - 1)) * Dd + d];
        if (cl > 0) s += sat[(((size_t)(rl - 1) * Ww) + (cl - 1)) * Dd + d];
    }

    float count = (float)((rh - rl) * (ch - cl));
    out[(size_t)n * Dd + d] = s / count;
}

// ---------------------------------------------------------------------------
// Fallback (only if ws too small for the 64 MiB SAT): direct summation.
// ---------------------------------------------------------------------------
__global__ void __launch_bounds__(256) roi_pool_naive(const float* __restrict__ feat,
                                                      const float* __restrict__ boxes,
                                                      float* __restrict__ out) {
    int n = blockIdx.x;
    int d = threadIdx.x;

    float x1 = boxes[n * 4 + 0];
    float y1 = boxes[n * 4 + 1];
    float x2 = boxes[n * 4 + 2];
    float y2 = boxes[n * 4 + 3];

    int cl = max(0, (int)floorf(x1 * 256.0f));
    int ch = (int)rintf(x2 * 256.0f + 0.5f);
    ch = min(Ww, max(cl + 1, ch));
    int rl = max(0, (int)floorf(y1 * 256.0f));
    int rh = (int)rintf(y2 * 256.0f + 0.5f);
    rh = min(Hh, max(rl + 1, rh));

    float s = 0.0f;
    for (int r = rl; r < rh; ++r) {
        const float* row = feat + ((size_t)r * Ww) * Dd + d;
        for (int c = cl; c < ch; ++c) s += row[(size_t)c * Dd];
    }
    float count = (float)((rh - rl) * (ch - cl));
    out[(size_t)n * Dd + d] = s / count;
}

extern "C" void kernel_launch(void* const* d_in, const int* in_sizes, int n_in,
                              void* d_out, int out_size, void* d_ws, size_t ws_size,
                              hipStream_t stream) {
    const float* feat  = (const float*)d_in[0];   // (256,256,256) f32
    const float* boxes = (const float*)d_in[1];   // (2048,4) f32
    float* out = (float*)d_out;                   // (2048,256) f32

    const size_t sat_bytes = (size_t)Hh * Ww * Dd * sizeof(float);  // 64 MiB

    if (ws_size >= sat_bytes) {
        float* sat = (float*)d_ws;
        sat_row_prefix<<<Hh * (Dd / DL), 1024, 0, stream>>>(feat, sat);
        sat_col_prefix<<<Ww * (Dd / DL), 1024, 0, stream>>>(sat);
        roi_pool_sat<<<(NB * Dd) / 256, 256, 0, stream>>>(sat, boxes, out);
    } else {
        roi_pool_naive<<<NB, 256, 0, stream>>>(feat, boxes, out);
    }
}